// Round 12
// baseline (97.937 us; speedup 1.0000x reference)
//
#include <hip/hip_runtime.h>
#include <hip/hip_bf16.h>

#define C_DIM 64
#define N_TOK 4608
#define PBLK  144      // proj blocks per batch (32 tokens each)
#define B_SZ  2
#define M64BLKS 72     // attn m-blocks per batch (64 m-tokens each)
#define NSEG  8        // n-segments == waves per attn block
#define SEGLEN (N_TOK / NSEG)   // 576
#define KTILES 288     // N_TOK/16 swizzled 16-row K/Q tiles per batch
#define VTILES 72      // N_TOK/64 swizzled 64-token V tiles per batch
#define OSTR  68       // o_lds padded stride (floats)

typedef __bf16 bf16x8 __attribute__((ext_vector_type(8)));
typedef float  f32x4  __attribute__((ext_vector_type(4)));

// ---------------------------------------------------------------------------
// Round 12: proj restructured — 288 blocks x 384 thr (6 waves = 6 tasks:
// {q,k,v} x {2 subtiles}), weight fragments loaded DIRECTLY from global
// (no weight LDS, no extra barrier; W rows are fragment-shaped). attn
// unchanged (M=64, 8.5 us, R11). Layouts identical to verified round 7.
// ---------------------------------------------------------------------------

__global__ __launch_bounds__(384) void proj_kernel(
    const float* __restrict__ x,  const float* __restrict__ h,
    const float* __restrict__ Wq, const float* __restrict__ bq,
    const float* __restrict__ Wk, const float* __restrict__ bk,
    const float* __restrict__ Wv, const float* __restrict__ bv,
    __hip_bfloat16* __restrict__ qS, __hip_bfloat16* __restrict__ kS,
    __hip_bfloat16* __restrict__ vS)
{
    __shared__ __hip_bfloat16 xt[32 * 72];   // x^T bf16 [n][c]
    __shared__ __hip_bfloat16 ht[32 * 72];   // h^T bf16 [n][c]
    __shared__ __hip_bfloat16 vl[64 * 36];   // v staging [c][n32]

    const int b  = blockIdx.x / PBLK;
    const int n0 = (blockIdx.x % PBLK) * 32;
    const int t  = threadIdx.x;

    // ---- stage x,h transposed: 512 float4 chunks each ----
    for (int ch = t; ch < 1024; ch += 384) {
        const bool isx = ch < 512;
        const int  c2  = isx ? ch : ch - 512;
        const int  c   = c2 >> 3, n4 = (c2 & 7) * 4;
        const float* src = isx ? x : h;
        __hip_bfloat16* dst = isx ? xt : ht;
        float4 v4 = *(const float4*)(src + (size_t)(b * C_DIM + c) * N_TOK + n0 + n4);
        dst[(n4 + 0) * 72 + c] = __float2bfloat16(v4.x);
        dst[(n4 + 1) * 72 + c] = __float2bfloat16(v4.y);
        dst[(n4 + 2) * 72 + c] = __float2bfloat16(v4.z);
        dst[(n4 + 3) * 72 + c] = __float2bfloat16(v4.w);
    }
    __syncthreads();

    const int wave = t >> 6, lane = t & 63;
    const int col = lane & 15, quad = lane >> 4;
    const int mat = wave >> 1;          // 0=q, 1=k, 2=v
    const int sub = wave & 1;           // 16-token subtile

    // B-operand fragments from LDS
    const __hip_bfloat16* srcT = (mat == 0) ? xt : ht;
    bf16x8 bin[2];
    #pragma unroll
    for (int kh = 0; kh < 2; kh++)
        bin[kh] = *(const bf16x8*)(srcT + (sub * 16 + col) * 72 + kh * 32 + quad * 8);

    // A-operand fragments DIRECT from global W (row-major = fragment-shaped)
    const float* W    = (mat == 0) ? Wq : ((mat == 1) ? Wk : Wv);
    const float* bias = (mat == 0) ? bq : ((mat == 1) ? bk : bv);

    f32x4 acc[4];
    #pragma unroll
    for (int ot = 0; ot < 4; ot++) {
        f32x4 a = (f32x4){0.f, 0.f, 0.f, 0.f};
        #pragma unroll
        for (int kh = 0; kh < 2; kh++) {
            const float* wp = W + (ot * 16 + col) * 64 + kh * 32 + quad * 8;
            float4 w0 = *(const float4*)(wp);
            float4 w1 = *(const float4*)(wp + 4);
            union { __hip_bfloat16 e[8]; bf16x8 v; } wf;
            wf.e[0] = __float2bfloat16(w0.x); wf.e[1] = __float2bfloat16(w0.y);
            wf.e[2] = __float2bfloat16(w0.z); wf.e[3] = __float2bfloat16(w0.w);
            wf.e[4] = __float2bfloat16(w1.x); wf.e[5] = __float2bfloat16(w1.y);
            wf.e[6] = __float2bfloat16(w1.z); wf.e[7] = __float2bfloat16(w1.w);
            a = __builtin_amdgcn_mfma_f32_16x16x32_bf16(wf.v, bin[kh], a, 0, 0, 0);
        }
        float4 b4 = *(const float4*)(bias + ot * 16 + quad * 4);
        a[0] += b4.x; a[1] += b4.y; a[2] += b4.z; a[3] += b4.w;
        acc[ot] = a;
    }

    const int half32 = (n0 >> 5) & 1;
    const int tile64 = n0 >> 6;

    if (mat == 0) {
        // q -> qS (row = col), scaled for exp2
        const size_t tile16 = (size_t)b * KTILES + (n0 >> 4) + sub;
        const float SC = 0.125f * 1.44269504088896f;
        #pragma unroll
        for (int ot = 0; ot < 4; ot++) {
            union { __hip_bfloat16 e[4]; uint2 v; } pk;
            #pragma unroll
            for (int r = 0; r < 4; r++) pk.e[r] = __float2bfloat16(acc[ot][r] * SC);
            *(uint2*)(qS + (tile16 << 10) + (ot >> 1) * 512 +
                      ((ot * 2 + (quad >> 1)) & 3) * 128 + col * 8 +
                      (quad & 1) * 4) = pk.v;
        }
    } else if (mat == 1) {
        // k -> kS with PV-matched token permutation (y = half32*32+sub*16+col)
        const int t_l = half32 * 2 + ((col >> 2) & 1);
        const int row = ((sub * 2 + (col >> 3)) & 3) * 4 + (col & 3);
        const size_t tile16 = (size_t)b * KTILES + tile64 * 4 + t_l;
        #pragma unroll
        for (int ot = 0; ot < 4; ot++) {
            union { __hip_bfloat16 e[4]; uint2 v; } pk;
            #pragma unroll
            for (int r = 0; r < 4; r++) pk.e[r] = __float2bfloat16(acc[ot][r]);
            *(uint2*)(kS + (tile16 << 10) + (ot >> 1) * 512 +
                      ((ot * 2 + (quad >> 1)) & 3) * 128 + row * 8 +
                      (quad & 1) * 4) = pk.v;
        }
    } else {
        // v -> vl LDS [c][n32]
        #pragma unroll
        for (int ot = 0; ot < 4; ot++)
            #pragma unroll
            for (int r = 0; r < 4; r++)
                vl[(ot * 16 + quad * 4 + r) * 36 + sub * 16 + col] =
                    __float2bfloat16(acc[ot][r]);
    }
    __syncthreads();
    if (t < 256) {   // gather v into swizzled vS (32x64/8 = 256 chunks)
        const int cc = t >> 6, qd = (t >> 4) & 3, c2 = t & 15;
        *(uint4*)(vS + (((size_t)b * VTILES + tile64) << 12) + cc * 1024 +
                  half32 * 512 + qd * 128 + c2 * 8) =
            *(const uint4*)(vl + (cc * 16 + c2) * 36 + qd * 8);
    }
}

// ---------------------------------------------------------------------------
// Flash attention, M=64 per block (unchanged from round 11: 8.5 us).
// ---------------------------------------------------------------------------
__global__ __launch_bounds__(512) void attn_kernel(
    const __hip_bfloat16* __restrict__ qS,
    const __hip_bfloat16* __restrict__ kS,
    const __hip_bfloat16* __restrict__ vS,
    float* __restrict__ out)
{
    __shared__ float o_lds[NSEG * 16 * OSTR];
    __shared__ float lstat[NSEG][64];

    const int b    = blockIdx.x / M64BLKS;
    const int mblk = blockIdx.x % M64BLKS;
    const int wave = threadIdx.x >> 6;
    const int lane = threadIdx.x & 63;
    const int col  = lane & 15;
    const int quad = lane >> 4;
    const int m0   = mblk * 64;

    const __hip_bfloat16* qp =
        qS + (((size_t)b * KTILES + (m0 >> 4)) << 10) + lane * 8;
    bf16x8 qa[4][2];
    #pragma unroll
    for (int ms = 0; ms < 4; ms++) {
        qa[ms][0] = *(const bf16x8*)(qp + ms * 1024);
        qa[ms][1] = *(const bf16x8*)(qp + ms * 1024 + 512);
    }

    f32x4 accO[4][4];
    #pragma unroll
    for (int ms = 0; ms < 4; ms++)
        #pragma unroll
        for (int cc = 0; cc < 4; cc++)
            accO[ms][cc] = (f32x4){0.f, 0.f, 0.f, 0.f};
    float rsum[4] = {0.f, 0.f, 0.f, 0.f};

    const int nbeg = wave * SEGLEN;

    #pragma unroll 1
    for (int n0 = nbeg; n0 < nbeg + SEGLEN; n0 += 64) {
        const __hip_bfloat16* kt =
            kS + (((size_t)b * KTILES + (n0 >> 4)) << 10) + lane * 8;
        bf16x8 ka[8];
        #pragma unroll
        for (int j = 0; j < 4; j++) {
            ka[2 * j]     = *(const bf16x8*)(kt + (j << 10));
            ka[2 * j + 1] = *(const bf16x8*)(kt + (j << 10) + 512);
        }
        const __hip_bfloat16* vt =
            vS + ((((size_t)b * VTILES) + (n0 >> 6)) << 12) + lane * 8;
        bf16x8 va[8];
        #pragma unroll
        for (int cc = 0; cc < 4; cc++) {
            va[2 * cc]     = *(const bf16x8*)(vt + cc * 1024);
            va[2 * cc + 1] = *(const bf16x8*)(vt + cc * 1024 + 512);
        }

        #pragma unroll
        for (int ms = 0; ms < 4; ms++) {
            f32x4 s[4];
            #pragma unroll
            for (int j = 0; j < 4; j++) {
                s[j] = __builtin_amdgcn_mfma_f32_16x16x32_bf16(
                           ka[2 * j], qa[ms][0], (f32x4){0.f, 0.f, 0.f, 0.f}, 0, 0, 0);
                s[j] = __builtin_amdgcn_mfma_f32_16x16x32_bf16(
                           ka[2 * j + 1], qa[ms][1], s[j], 0, 0, 0);
            }
            union { __hip_bfloat16 e[8]; bf16x8 v; } p0, p1;
            float ps = 0.f;
            #pragma unroll
            for (int j = 0; j < 2; j++)
                #pragma unroll
                for (int r = 0; r < 4; r++) {
                    float e0 = __builtin_amdgcn_exp2f(s[j][r]);
                    float e1 = __builtin_amdgcn_exp2f(s[2 + j][r]);
                    ps += e0 + e1;
                    p0.e[j * 4 + r] = __float2bfloat16(e0);
                    p1.e[j * 4 + r] = __float2bfloat16(e1);
                }
            rsum[ms] += ps;
            #pragma unroll
            for (int cc = 0; cc < 4; cc++) {
                accO[ms][cc] = __builtin_amdgcn_mfma_f32_16x16x32_bf16(
                                   va[2 * cc], p0.v, accO[ms][cc], 0, 0, 0);
                accO[ms][cc] = __builtin_amdgcn_mfma_f32_16x16x32_bf16(
                                   va[2 * cc + 1], p1.v, accO[ms][cc], 0, 0, 0);
            }
        }
    }

    #pragma unroll
    for (int ms = 0; ms < 4; ms++) {
        rsum[ms] += __shfl_xor(rsum[ms], 16);
        rsum[ms] += __shfl_xor(rsum[ms], 32);
    }
    if (quad == 0) {
        #pragma unroll
        for (int ms = 0; ms < 4; ms++) lstat[wave][ms * 16 + col] = rsum[ms];
    }

    #pragma unroll
    for (int phase = 0; phase < 4; phase++) {
        #pragma unroll
        for (int cc = 0; cc < 4; cc++)
            *(f32x4*)(o_lds + (wave * 16 + col) * OSTR + cc * 16 + quad * 4) =
                accO[phase][cc];
        __syncthreads();
        if (threadIdx.x < 256) {
            const int m  = threadIdx.x & 15;
            const int cq = threadIdx.x >> 4;
            const int mi = phase * 16 + m;
            float lsum = 0.f;
            f32x4 oacc = (f32x4){0.f, 0.f, 0.f, 0.f};
            #pragma unroll
            for (int sgm = 0; sgm < NSEG; sgm++) {
                lsum += lstat[sgm][mi];
                oacc += *(const f32x4*)(o_lds + (sgm * 16 + m) * OSTR + cq * 4);
            }
            const float inv = 1.0f / lsum;
            #pragma unroll
            for (int r = 0; r < 4; r++) {
                const int c = cq * 4 + r;
                out[(size_t)(b * C_DIM + c) * N_TOK + m0 + phase * 16 + m] =
                    oacc[r] * inv;
            }
        }
        __syncthreads();
    }
}

extern "C" void kernel_launch(void* const* d_in, const int* in_sizes, int n_in,
                              void* d_out, int out_size, void* d_ws, size_t ws_size,
                              hipStream_t stream) {
    const float* x  = (const float*)d_in[0];
    const float* h  = (const float*)d_in[1];
    const float* Wq = (const float*)d_in[2];
    const float* bq = (const float*)d_in[3];
    const float* Wk = (const float*)d_in[4];
    const float* bk = (const float*)d_in[5];
    const float* Wv = (const float*)d_in[6];
    const float* bv = (const float*)d_in[7];
    float* out = (float*)d_out;

    const size_t elems = (size_t)B_SZ * N_TOK * C_DIM;   // 589824
    __hip_bfloat16* qS = (__hip_bfloat16*)d_ws;
    __hip_bfloat16* kS = qS + elems;
    __hip_bfloat16* vS = kS + elems;

    proj_kernel<<<B_SZ * PBLK, 384, 0, stream>>>(x, h, Wq, bq, Wk, bk, Wv, bv,
                                                 qS, kS, vS);
    attn_kernel<<<B_SZ * M64BLKS, 512, 0, stream>>>(qS, kS, vS, out);
}

// Round 13
// 93.687 us; speedup vs baseline: 1.0454x; 1.0454x over previous
//
#include <hip/hip_runtime.h>
#include <hip/hip_bf16.h>

#define C_DIM 64
#define N_TOK 4608
#define NBLK  72       // proj blocks per batch (64 tokens each)
#define B_SZ  2
#define M64BLKS 72     // attn m-blocks per batch (64 m-tokens each)
#define NSEG  8        // n-segments == waves per attn block
#define SEGLEN (N_TOK / NSEG)   // 576
#define KTILES 288     // N_TOK/16 swizzled 16-row K/Q tiles per batch
#define VTILES 72      // N_TOK/64 swizzled 64-token V tiles per batch
#define OSTR  68       // o_lds padded stride (floats)

typedef __bf16 bf16x8 __attribute__((ext_vector_type(8)));
typedef float  f32x4  __attribute__((ext_vector_type(4)));

// ---------------------------------------------------------------------------
// Round 13 = exact revert to round 11 (best: 93.35 us, absmax 0.00390625).
// R12's direct-global weight fragments regressed proj 4.8 -> 9.4 us
// (serialized L2-latency chain at 1.7 waves/SIMD); LDS-staged weights win.
// Layouts (verified R7): kS token-permuted so S^T C/D regs are already PV
// B-operand fragments; vS fragment-swizzled; no-max softmax (log2 domain).
// ---------------------------------------------------------------------------

__device__ __forceinline__ void gemm_tile(
    const __hip_bfloat16* wmat, const bf16x8 bin[2], const float* bias,
    int col, int quad, f32x4 acc[4])
{
    #pragma unroll
    for (int ot = 0; ot < 4; ot++) {
        f32x4 a = (f32x4){0.f, 0.f, 0.f, 0.f};
        #pragma unroll
        for (int kh = 0; kh < 2; kh++) {
            bf16x8 wf = *(const bf16x8*)(wmat + (ot * 16 + col) * 72 +
                                         kh * 32 + quad * 8);
            a = __builtin_amdgcn_mfma_f32_16x16x32_bf16(wf, bin[kh], a, 0, 0, 0);
        }
        float4 b4 = *(const float4*)(bias + ot * 16 + quad * 4);
        a[0] += b4.x; a[1] += b4.y; a[2] += b4.z; a[3] += b4.w;
        acc[ot] = a;
    }
}

__global__ __launch_bounds__(256) void proj_kernel(
    const float* __restrict__ x,  const float* __restrict__ h,
    const float* __restrict__ Wq, const float* __restrict__ bq,
    const float* __restrict__ Wk, const float* __restrict__ bk,
    const float* __restrict__ Wv, const float* __restrict__ bv,
    __hip_bfloat16* __restrict__ qS, __hip_bfloat16* __restrict__ kS,
    __hip_bfloat16* __restrict__ vS)
{
    __shared__ __hip_bfloat16 wl[3 * 64 * 72];
    __shared__ __hip_bfloat16 xt[64 * 72];
    __shared__ __hip_bfloat16 ht[64 * 72];
    __shared__ __hip_bfloat16 vl[64 * 72];

    const int b  = blockIdx.x / NBLK;
    const int n0 = (blockIdx.x % NBLK) * 64;
    const int t  = threadIdx.x;

    #pragma unroll
    for (int mat = 0; mat < 3; mat++) {
        const float* W = (mat == 0) ? Wq : ((mat == 1) ? Wk : Wv);
        __hip_bfloat16* wd = wl + mat * (64 * 72);
        #pragma unroll
        for (int i = 0; i < 4; i++) {
            const int ch = i * 256 + t;
            const int o = ch >> 4, c0 = (ch & 15) * 4;
            float4 w4 = *(const float4*)(W + ch * 4);
            union { __hip_bfloat16 e[4]; uint2 v; } pk;
            pk.e[0] = __float2bfloat16(w4.x); pk.e[1] = __float2bfloat16(w4.y);
            pk.e[2] = __float2bfloat16(w4.z); pk.e[3] = __float2bfloat16(w4.w);
            *(uint2*)(wd + o * 72 + c0) = pk.v;
        }
    }
    #pragma unroll
    for (int i = 0; i < 4; i++) {
        const int ch = i * 256 + t;
        const int c = ch >> 4, n4 = (ch & 15) * 4;
        float4 x4 = *(const float4*)(x + (size_t)(b * C_DIM + c) * N_TOK + n0 + n4);
        float4 h4 = *(const float4*)(h + (size_t)(b * C_DIM + c) * N_TOK + n0 + n4);
        xt[(n4 + 0) * 72 + c] = __float2bfloat16(x4.x);
        xt[(n4 + 1) * 72 + c] = __float2bfloat16(x4.y);
        xt[(n4 + 2) * 72 + c] = __float2bfloat16(x4.z);
        xt[(n4 + 3) * 72 + c] = __float2bfloat16(x4.w);
        ht[(n4 + 0) * 72 + c] = __float2bfloat16(h4.x);
        ht[(n4 + 1) * 72 + c] = __float2bfloat16(h4.y);
        ht[(n4 + 2) * 72 + c] = __float2bfloat16(h4.z);
        ht[(n4 + 3) * 72 + c] = __float2bfloat16(h4.w);
    }
    __syncthreads();

    const int wave = t >> 6, lane = t & 63;
    const int col = lane & 15, quad = lane >> 4;

    bf16x8 xb[2], hb[2];
    #pragma unroll
    for (int kh = 0; kh < 2; kh++) {
        xb[kh] = *(const bf16x8*)(xt + (wave * 16 + col) * 72 + kh * 32 + quad * 8);
        hb[kh] = *(const bf16x8*)(ht + (wave * 16 + col) * 72 + kh * 32 + quad * 8);
    }

    f32x4 acc[4];

    gemm_tile(wl + 0 * (64 * 72), xb, bq, col, quad, acc);
    {
        const size_t tile16 = (size_t)b * KTILES + (n0 >> 4) + wave;
        const float SC = 0.125f * 1.44269504088896f;
        #pragma unroll
        for (int ot = 0; ot < 4; ot++) {
            union { __hip_bfloat16 e[4]; uint2 v; } pk;
            #pragma unroll
            for (int r = 0; r < 4; r++) pk.e[r] = __float2bfloat16(acc[ot][r] * SC);
            *(uint2*)(qS + (tile16 << 10) + (ot >> 1) * 512 +
                      ((ot * 2 + (quad >> 1)) & 3) * 128 + col * 8 +
                      (quad & 1) * 4) = pk.v;
        }
    }

    gemm_tile(wl + 1 * (64 * 72), hb, bk, col, quad, acc);
    {
        const int t_l = (wave >> 1) * 2 + ((col >> 2) & 1);
        const int row = ((wave * 2 + (col >> 3)) & 3) * 4 + (col & 3);
        const size_t tile16 = (size_t)b * KTILES + (n0 >> 4) + t_l;
        #pragma unroll
        for (int ot = 0; ot < 4; ot++) {
            union { __hip_bfloat16 e[4]; uint2 v; } pk;
            #pragma unroll
            for (int r = 0; r < 4; r++) pk.e[r] = __float2bfloat16(acc[ot][r]);
            *(uint2*)(kS + (tile16 << 10) + (ot >> 1) * 512 +
                      ((ot * 2 + (quad >> 1)) & 3) * 128 + row * 8 +
                      (quad & 1) * 4) = pk.v;
        }
    }

    gemm_tile(wl + 2 * (64 * 72), hb, bv, col, quad, acc);
    #pragma unroll
    for (int ot = 0; ot < 4; ot++)
        #pragma unroll
        for (int r = 0; r < 4; r++)
            vl[(ot * 16 + quad * 4 + r) * 72 + wave * 16 + col] =
                __float2bfloat16(acc[ot][r]);
    __syncthreads();
    {
        const size_t vbase = ((size_t)(b * VTILES) + (n0 >> 6)) << 12;
        #pragma unroll
        for (int rep = 0; rep < 2; rep++) {
            const int ch = rep * 256 + t;
            const int cc = ch >> 7, hf = (ch >> 6) & 1;
            const int qd = (ch >> 4) & 3, c2 = ch & 15;
            *(uint4*)(vS + vbase + (size_t)ch * 8) =
                *(const uint4*)(vl + (cc * 16 + c2) * 72 + hf * 32 + qd * 8);
        }
    }
}

__global__ __launch_bounds__(512) void attn_kernel(
    const __hip_bfloat16* __restrict__ qS,
    const __hip_bfloat16* __restrict__ kS,
    const __hip_bfloat16* __restrict__ vS,
    float* __restrict__ out)
{
    __shared__ float o_lds[NSEG * 16 * OSTR];
    __shared__ float lstat[NSEG][64];

    const int b    = blockIdx.x / M64BLKS;
    const int mblk = blockIdx.x % M64BLKS;
    const int wave = threadIdx.x >> 6;
    const int lane = threadIdx.x & 63;
    const int col  = lane & 15;
    const int quad = lane >> 4;
    const int m0   = mblk * 64;

    const __hip_bfloat16* qp =
        qS + (((size_t)b * KTILES + (m0 >> 4)) << 10) + lane * 8;
    bf16x8 qa[4][2];
    #pragma unroll
    for (int ms = 0; ms < 4; ms++) {
        qa[ms][0] = *(const bf16x8*)(qp + ms * 1024);
        qa[ms][1] = *(const bf16x8*)(qp + ms * 1024 + 512);
    }

    f32x4 accO[4][4];
    #pragma unroll
    for (int ms = 0; ms < 4; ms++)
        #pragma unroll
        for (int cc = 0; cc < 4; cc++)
            accO[ms][cc] = (f32x4){0.f, 0.f, 0.f, 0.f};
    float rsum[4] = {0.f, 0.f, 0.f, 0.f};

    const int nbeg = wave * SEGLEN;

    #pragma unroll 1
    for (int n0 = nbeg; n0 < nbeg + SEGLEN; n0 += 64) {
        const __hip_bfloat16* kt =
            kS + (((size_t)b * KTILES + (n0 >> 4)) << 10) + lane * 8;
        bf16x8 ka[8];
        #pragma unroll
        for (int j = 0; j < 4; j++) {
            ka[2 * j]     = *(const bf16x8*)(kt + (j << 10));
            ka[2 * j + 1] = *(const bf16x8*)(kt + (j << 10) + 512);
        }
        const __hip_bfloat16* vt =
            vS + ((((size_t)b * VTILES) + (n0 >> 6)) << 12) + lane * 8;
        bf16x8 va[8];
        #pragma unroll
        for (int cc = 0; cc < 4; cc++) {
            va[2 * cc]     = *(const bf16x8*)(vt + cc * 1024);
            va[2 * cc + 1] = *(const bf16x8*)(vt + cc * 1024 + 512);
        }

        #pragma unroll
        for (int ms = 0; ms < 4; ms++) {
            f32x4 s[4];
            #pragma unroll
            for (int j = 0; j < 4; j++) {
                s[j] = __builtin_amdgcn_mfma_f32_16x16x32_bf16(
                           ka[2 * j], qa[ms][0], (f32x4){0.f, 0.f, 0.f, 0.f}, 0, 0, 0);
                s[j] = __builtin_amdgcn_mfma_f32_16x16x32_bf16(
                           ka[2 * j + 1], qa[ms][1], s[j], 0, 0, 0);
            }
            union { __hip_bfloat16 e[8]; bf16x8 v; } p0, p1;
            float ps = 0.f;
            #pragma unroll
            for (int j = 0; j < 2; j++)
                #pragma unroll
                for (int r = 0; r < 4; r++) {
                    float e0 = __builtin_amdgcn_exp2f(s[j][r]);
                    float e1 = __builtin_amdgcn_exp2f(s[2 + j][r]);
                    ps += e0 + e1;
                    p0.e[j * 4 + r] = __float2bfloat16(e0);
                    p1.e[j * 4 + r] = __float2bfloat16(e1);
                }
            rsum[ms] += ps;
            #pragma unroll
            for (int cc = 0; cc < 4; cc++) {
                accO[ms][cc] = __builtin_amdgcn_mfma_f32_16x16x32_bf16(
                                   va[2 * cc], p0.v, accO[ms][cc], 0, 0, 0);
                accO[ms][cc] = __builtin_amdgcn_mfma_f32_16x16x32_bf16(
                                   va[2 * cc + 1], p1.v, accO[ms][cc], 0, 0, 0);
            }
        }
    }

    #pragma unroll
    for (int ms = 0; ms < 4; ms++) {
        rsum[ms] += __shfl_xor(rsum[ms], 16);
        rsum[ms] += __shfl_xor(rsum[ms], 32);
    }
    if (quad == 0) {
        #pragma unroll
        for (int ms = 0; ms < 4; ms++) lstat[wave][ms * 16 + col] = rsum[ms];
    }

    #pragma unroll
    for (int phase = 0; phase < 4; phase++) {
        #pragma unroll
        for (int cc = 0; cc < 4; cc++)
            *(f32x4*)(o_lds + (wave * 16 + col) * OSTR + cc * 16 + quad * 4) =
                accO[phase][cc];
        __syncthreads();
        if (threadIdx.x < 256) {
            const int m  = threadIdx.x & 15;
            const int cq = threadIdx.x >> 4;
            const int mi = phase * 16 + m;
            float lsum = 0.f;
            f32x4 oacc = (f32x4){0.f, 0.f, 0.f, 0.f};
            #pragma unroll
            for (int sgm = 0; sgm < NSEG; sgm++) {
                lsum += lstat[sgm][mi];
                oacc += *(const f32x4*)(o_lds + (sgm * 16 + m) * OSTR + cq * 4);
            }
            const float inv = 1.0f / lsum;
            #pragma unroll
            for (int r = 0; r < 4; r++) {
                const int c = cq * 4 + r;
                out[(size_t)(b * C_DIM + c) * N_TOK + m0 + phase * 16 + m] =
                    oacc[r] * inv;
            }
        }
        __syncthreads();
    }
}

extern "C" void kernel_launch(void* const* d_in, const int* in_sizes, int n_in,
                              void* d_out, int out_size, void* d_ws, size_t ws_size,
                              hipStream_t stream) {
    const float* x  = (const float*)d_in[0];
    const float* h  = (const float*)d_in[1];
    const float* Wq = (const float*)d_in[2];
    const float* bq = (const float*)d_in[3];
    const float* Wk = (const float*)d_in[4];
    const float* bk = (const float*)d_in[5];
    const float* Wv = (const float*)d_in[6];
    const float* bv = (const float*)d_in[7];
    float* out = (float*)d_out;

    const size_t elems = (size_t)B_SZ * N_TOK * C_DIM;   // 589824
    __hip_bfloat16* qS = (__hip_bfloat16*)d_ws;
    __hip_bfloat16* kS = qS + elems;
    __hip_bfloat16* vS = kS + elems;

    proj_kernel<<<B_SZ * NBLK, 256, 0, stream>>>(x, h, Wq, bq, Wk, bk, Wv, bv,
                                                 qS, kS, vS);
    attn_kernel<<<B_SZ * M64BLKS, 512, 0, stream>>>(qS, kS, vS, out);
}